// Round 14
// baseline (510.103 us; speedup 1.0000x reference)
//
#include <hip/hip_runtime.h>

#define NUM_K   4096
#define CDIM    64
#define HWDIM   4096            // 64*64
#define NVEC    65536           // 16 * 64 * 64
#define CHW     (CDIM * HWDIM)  // 262144
#define KT      32              // codes per k-tile
#define NKT_SL  64              // k-tiles per slice (2048 codes)
// rescue margin on biased s/2 scale: bf16-split budget 2e-3 (validated r4-r6)
// + 7-bit mask granularity q<=3.9e-3 (scores < 512) + slack
#define TAUH    6e-3f
#define SBIAS   128.0f          // score bias: s' = 128 + (wsq - 2 x.w)/2 > 0 always

// ---- output layout (floats, concatenated in reference return order) ----
#define O_Q     0               // quantized_ste  [16,64,64,64] = 4194304
#define O_LOSS  4194304         // scalar
#define O_IDX   4194305         // encoding_indices [16,64,64] = 65536 (as float)
#define O_W     4259841         // new_weight   [4096,64] = 262144
#define O_CS    4521985         // new_cluster_size [4096]
#define O_EW    4526081         // new_ema_w    [4096,64] = 262144
// Scratch overlays in out (strictly ordered, r8/r11-proven placement):
//  - wh/wl bf16 codebook: out floats [0, 262144)  (prep W -> argmin R ->
//    overwritten by tail phase-1's O_Q writes)
//  - keys[2][NVEC] u64: out floats [4259842, 4521986)  (argmin W -> tail
//    phase-1 R -> phase-3 overwrites, ordered by grid barriers)
//  - b2s[2][NVEC] f32:  out floats [4521986, 4653058)  (same ordering)

// ---- workspace layout (floats) ----
#define W_WSQ    0               // wsq/2 + SBIAS [4096]
#define W_CNT0   4096            // counts replica 0 [4096]
#define W_CNT1   8192            // counts replica 1 [4096]
#define W_LOSS   12288           // loss
#define W_ESUM   12289           // sum(ema_cluster_size)
#define W_RCNT   12290           // flagged count
#define W_BAR0   12291           // grid barrier counter 0
#define W_BAR1   12292           // grid barrier counter 1
#define W_RLIST  12296           // flagged-vector list int[65536] (worst case)
#define W_DW0    77832           // dw replica 0 [262144]
#define W_DW1    339976          // dw replica 1 [262144]
// high-water: 602120 floats = 2.41 MB (under proven 2.92 MB)

typedef unsigned long long u64;
typedef __bf16 bf16x8 __attribute__((ext_vector_type(8)));
typedef float  f32x4  __attribute__((ext_vector_type(4)));

__device__ __forceinline__ unsigned f2ord(float f) {
    unsigned u = __float_as_uint(f);
    return (u & 0x80000000u) ? ~u : (u | 0x80000000u);
}
__device__ __forceinline__ unsigned umn(unsigned a, unsigned b) { return a < b ? a : b; }
__device__ __forceinline__ unsigned umx(unsigned a, unsigned b) { return a > b ? a : b; }

// Per codebook row: biased wsq/2 + SBIAS (fp32) + bf16 hi/lo split copies.
// Zeroes counts replicas + loss/esum/rcnt + BOTH grid-barrier counters
// (graph-replay safe) + both dw replicas (grid = CHW threads).
__global__ void __launch_bounds__(256)
prep_kernel(const float* __restrict__ w, float* __restrict__ wsqh,
            __bf16* __restrict__ wh, __bf16* __restrict__ wl,
            float* __restrict__ zero_area,
            float* __restrict__ dw0, float* __restrict__ dw1) {
    int gid = blockIdx.x * 256 + threadIdx.x;
    dw0[gid] = 0.f;                            // gid in [0, CHW)
    dw1[gid] = 0.f;
    if (gid < 8200) zero_area[gid] = 0.f;      // counts0/1 + scalars + bars
    int wv = threadIdx.x >> 6, lane = threadIdx.x & 63;
    int row = blockIdx.x * 4 + wv;
    float v = w[row * CDIM + lane];
    __bf16 h = (__bf16)v;
    __bf16 l = (__bf16)(v - (float)h);         // v - hi exact in fp32
    wh[row * CDIM + lane] = h;
    wl[row * CDIM + lane] = l;
    float sq = v * v;
#pragma unroll
    for (int m = 1; m < 64; m <<= 1) sq += __shfl_xor(sq, m, 64);
    if (lane == 0) wsqh[row] = 0.5f * sq + SBIAS;
}

// One k-tile body: 48 MFMA (4 m-slots x 2 code-halves x bf16x3-split K=64)
// + packed-u32 top-2 update. Identical numerics to the verified kernel.
__device__ __forceinline__ void kt_body(const bf16x8 (&B)[8],
                                        const bf16x8 (&ah)[4][2],
                                        const bf16x8 (&al)[4][2],
                                        unsigned (&b1k)[16], unsigned (&b2k)[16],
                                        float wA, float wB, int kt) {
    unsigned tA = (unsigned)(kt * 2), tB = tA + 1;
#pragma unroll
    for (int m = 0; m < 4; ++m) {
        f32x4 accA = {wA, wA, wA, wA};     // acc = SBIAS + wsq/2 - dot  (> 0)
        f32x4 accB = {wB, wB, wB, wB};
        accA = __builtin_amdgcn_mfma_f32_16x16x32_bf16(ah[m][0], B[0], accA, 0, 0, 0);
        accA = __builtin_amdgcn_mfma_f32_16x16x32_bf16(ah[m][1], B[1], accA, 0, 0, 0);
        accA = __builtin_amdgcn_mfma_f32_16x16x32_bf16(al[m][0], B[0], accA, 0, 0, 0);
        accA = __builtin_amdgcn_mfma_f32_16x16x32_bf16(al[m][1], B[1], accA, 0, 0, 0);
        accA = __builtin_amdgcn_mfma_f32_16x16x32_bf16(ah[m][0], B[4], accA, 0, 0, 0);
        accA = __builtin_amdgcn_mfma_f32_16x16x32_bf16(ah[m][1], B[5], accA, 0, 0, 0);
        accB = __builtin_amdgcn_mfma_f32_16x16x32_bf16(ah[m][0], B[2], accB, 0, 0, 0);
        accB = __builtin_amdgcn_mfma_f32_16x16x32_bf16(ah[m][1], B[3], accB, 0, 0, 0);
        accB = __builtin_amdgcn_mfma_f32_16x16x32_bf16(al[m][0], B[2], accB, 0, 0, 0);
        accB = __builtin_amdgcn_mfma_f32_16x16x32_bf16(al[m][1], B[3], accB, 0, 0, 0);
        accB = __builtin_amdgcn_mfma_f32_16x16x32_bf16(ah[m][0], B[6], accB, 0, 0, 0);
        accB = __builtin_amdgcn_mfma_f32_16x16x32_bf16(ah[m][1], B[7], accB, 0, 0, 0);
#pragma unroll
        for (int r = 0; r < 4; ++r) {
            unsigned ka = (__float_as_uint(accA[r]) & 0xFFFFFF80u) | tA;  // v_and_or_b32
            unsigned kb = (__float_as_uint(accB[r]) & 0xFFFFFF80u) | tB;
            unsigned lo = umn(ka, kb), hi = umx(ka, kb);
            int s8 = m * 4 + r;
            b2k[s8] = umn(umn(b2k[s8], umx(b1k[s8], lo)), hi);  // min3 fuse
            b1k[s8] = umn(b1k[s8], lo);
        }
    }
}

// Fused bf16x3-split MFMA GEMM + argmin, K-split into 2 slices (grid.y).
// FROZEN at the round-2 verified structure (113.5us best): 128 thr / 2 waves,
// 64 rows per wave (4 m-slots), reg-staged B ping-pong with per-kt barrier,
// unpadded xs with XOR swizzle (bank-conflict-free, 32 KB LDS).
__global__ void __launch_bounds__(128, 3)
argmin_mfma(const float* __restrict__ x,
            const __bf16* __restrict__ wh_g, const __bf16* __restrict__ wl_g,
            const float* __restrict__ wsqh_g,
            u64* __restrict__ keys, float* __restrict__ b2s) {
    extern __shared__ __bf16 smem[];           // 32768 B
    char* xs_h = (char*)smem;                  // [128 rows][128 B] swizzled
    char* xs_l = xs_h + 16384;
    __bf16* bs = smem;                         // overlay: [2][4096] after xs dead

    int t = threadIdx.x, wv = t >> 6, lane = t & 63;
    int n0 = blockIdx.x * 128;
    int b = n0 >> 12, hw0 = n0 & (HWDIM - 1);
    int kbase = blockIdx.y * (NUM_K / 2);
    int slice = blockIdx.y;

    // 1) stage -x hi/lo; row = t, 8 col-groups of 8 ch; b128 swizzled writes.
    {
        const float* xb = x + b * CHW + hw0 + t;
#pragma unroll
        for (int j = 0; j < 8; ++j) {
            bf16x8 hi, lo;
#pragma unroll
            for (int cc = 0; cc < 8; ++cc) {
                float v = -xb[(j * 8 + cc) * HWDIM];
                __bf16 h = (__bf16)v;
                hi[cc] = h;
                lo[cc] = (__bf16)(v - (float)h);   // exact in fp32
            }
            int bo = (t * 128 + j * 16) ^ ((t & 7) << 4);
            *(bf16x8*)(xs_h + bo) = hi;
            *(bf16x8*)(xs_l + bo) = lo;
        }
    }
    __syncthreads();

    int nn = lane & 15, q4 = lane >> 4;
    // 2) A-frags -> registers (64 rows per wave, 4 m-slots; swizzled b128 reads)
    bf16x8 ah[4][2], al[4][2];
#pragma unroll
    for (int m = 0; m < 4; ++m) {
        int id = wv * 64 + m * 16 + nn;
#pragma unroll
        for (int ch = 0; ch < 2; ++ch) {
            int bo = (id * 128 + (q4 + ch * 4) * 16) ^ ((id & 7) << 4);
            ah[m][ch] = *(const bf16x8*)(xs_h + bo);
            al[m][ch] = *(const bf16x8*)(xs_l + bo);
        }
    }
    __syncthreads();   // all waves done reading xs -> LDS reusable for B tiles

    // B staging map (128 thr, 4 chunks each): LDS layout per tile:
    // hiA [0,1024) hiB [1024,2048) loA [2048,3072) loB [3072,4096) elems;
    // writes at t*16 B consecutive (conflict-free); reads 16B/lane chunks.
    int sr = t & 15, sj = (t >> 4) & 7;
    long goff0 = (long)sr * 64 + sj * 8;        // codes 0-15 half
    long goff1 = (long)(16 + sr) * 64 + sj * 8; // codes 16-31 half
    {
        long g = (long)kbase * 64;
        *(bf16x8*)(bs + t * 8)        = *(const bf16x8*)(wh_g + g + goff0);
        *(bf16x8*)(bs + 1024 + t * 8) = *(const bf16x8*)(wh_g + g + goff1);
        *(bf16x8*)(bs + 2048 + t * 8) = *(const bf16x8*)(wl_g + g + goff0);
        *(bf16x8*)(bs + 3072 + t * 8) = *(const bf16x8*)(wl_g + g + goff1);
    }
    __syncthreads();

    unsigned b1k[16], b2k[16];
#pragma unroll
    for (int s = 0; s < 16; ++s) { b1k[s] = 0xFFFFFFFFu; b2k[s] = 0xFFFFFFFFu; }

    for (int kt = 0; kt < NKT_SL; ++kt) {
        __bf16* base = bs + (kt & 1) * 4096;
        bf16x8 st0h, st1h, st0l, st1l;
        bool pre = (kt + 1 < NKT_SL);
        if (pre) {   // issue next-tile global loads early; latency spans MFMA
            long g = (long)(kbase + (kt + 1) * KT) * 64;
            st0h = *(const bf16x8*)(wh_g + g + goff0);
            st1h = *(const bf16x8*)(wh_g + g + goff1);
            st0l = *(const bf16x8*)(wl_g + g + goff0);
            st1l = *(const bf16x8*)(wl_g + g + goff1);
        }

        int k0 = kbase + kt * KT;
        float wA = wsqh_g[k0 + nn];            // biased table, L1-hot
        float wB = wsqh_g[k0 + 16 + nn];

        int o1 = (q4 * 16 + nn) * 8, o2 = ((q4 + 4) * 16 + nn) * 8;
        bf16x8 B[8];
        B[0] = *(const bf16x8*)(base + o1);            // bh0A
        B[1] = *(const bf16x8*)(base + o2);            // bh1A
        B[2] = *(const bf16x8*)(base + 1024 + o1);     // bh0B
        B[3] = *(const bf16x8*)(base + 1024 + o2);     // bh1B
        B[4] = *(const bf16x8*)(base + 2048 + o1);     // bl0A
        B[5] = *(const bf16x8*)(base + 2048 + o2);     // bl1A
        B[6] = *(const bf16x8*)(base + 3072 + o1);     // bl0B
        B[7] = *(const bf16x8*)(base + 3072 + o2);     // bl1B

        kt_body(B, ah, al, b1k, b2k, wA, wB, kt);

        if (pre) {
            __bf16* nb = bs + ((kt + 1) & 1) * 4096;
            *(bf16x8*)(nb + t * 8)        = st0h;
            *(bf16x8*)(nb + 1024 + t * 8) = st1h;
            *(bf16x8*)(nb + 2048 + t * 8) = st0l;
            *(bf16x8*)(nb + 3072 + t * 8) = st1l;
        }
        __syncthreads();
    }

    // unpack: tag*16 == kt*32 + half*16, so code = (kbase+nn) + tag*16
    float s1[16], sb2[16]; int code[16];
#pragma unroll
    for (int s = 0; s < 16; ++s) {
        s1[s]  = __uint_as_float(b1k[s] & 0xFFFFFF80u);
        sb2[s] = __uint_as_float(b2k[s] & 0xFFFFFF80u);
        code[s] = (kbase + nn) + (int)(b1k[s] & 0x7Fu) * 16;
    }
    // cross-lane merge over the 16 code-classes (lanes sharing q4)
#pragma unroll
    for (int msk = 1; msk < 16; msk <<= 1) {
#pragma unroll
        for (int s = 0; s < 16; ++s) {
            float os1 = __shfl_xor(s1[s], msk, 64);
            float ob2 = __shfl_xor(sb2[s], msk, 64);
            int   oc  = __shfl_xor(code[s], msk, 64);
            sb2[s] = fminf(fminf(sb2[s], ob2), fmaxf(s1[s], os1));
            if (os1 < s1[s]) code[s] = oc;   // exact ties -> margin 0 -> rescued
            s1[s] = fminf(s1[s], os1);
        }
    }
    if (nn == 0) {
#pragma unroll
        for (int s = 0; s < 16; ++s) {
            int m = s >> 2, r = s & 3;
            int v = n0 + wv * 64 + m * 16 + q4 * 4 + r;
            keys[slice * NVEC + v] = ((u64)__float_as_uint(s1[s]) << 32) | (unsigned)code[s];
            b2s[slice * NVEC + v]  = sb2[s];
        }
    }
}

// Manual grid barrier (cg::grid_sync equivalent): __syncthreads drains the
// block's writes to L2; release __threadfence writes back L2 (cross-XCD);
// spin on device-scope atomic load; acquire __threadfence invalidates.
// SAFE only because all gridDim blocks are co-resident (see launch config).
__device__ __forceinline__ void grid_barrier(int* ctr) {
    __syncthreads();
    if (threadIdx.x == 0) {
        __threadfence();                       // release: wb L2
        __hip_atomic_fetch_add(ctr, 1, __ATOMIC_RELAXED, __HIP_MEMORY_SCOPE_AGENT);
        while (__hip_atomic_load(ctr, __ATOMIC_RELAXED, __HIP_MEMORY_SCOPE_AGENT)
               < (int)gridDim.x)
            __builtin_amdgcn_s_sleep(2);
        __threadfence();                       // acquire: inv caches
    }
    __syncthreads();
}

// ONE kernel = assign_fused -> grid_barrier -> rescue_patch -> grid_barrier
// -> finalize (bodies byte-identical to the r11/r13-verified kernels).
// Grid 1024x256, __launch_bounds__(256,4) caps VGPR at 128 -> 16 waves/CU
// -> exactly 4 blocks/CU x 256 CU = 1024 co-resident blocks (LDS ~18KB).
__global__ void __launch_bounds__(256, 4)
tail_fused(const float* __restrict__ x, const float* __restrict__ w,
           const u64* __restrict__ keys, const float* __restrict__ b2s,
           const float* __restrict__ wsqh, const float* __restrict__ ecs,
           const float* __restrict__ ema_w, float* __restrict__ esum,
           float* out,
           float* __restrict__ counts0, float* __restrict__ counts1,
           float* __restrict__ dw0, float* __restrict__ dw1,
           int* __restrict__ rcnt, int* __restrict__ rlist,
           float* __restrict__ loss_acc, int* __restrict__ bars) {
    __shared__ float xs[64][CDIM + 1];
    __shared__ int   sidx[64];
    __shared__ float red[256];
    // phase-2 scratch overlays the (then-dead) xs region:
    float* xv = &xs[0][0];                     // 64 floats
    u64*   rk = (u64*)&xs[2][0];               // 256 u64 (byte off 520, 8B-aligned)

    int t  = threadIdx.x;
    int blk = blockIdx.x;
    int lane = t & 63, wv = t >> 6;

    // ================= phase 1: combine + assign (r11-verified) =============
    {
        int n0 = blk * 64;
        int b  = n0 >> 12;
        int hw0 = n0 & (HWDIM - 1);
        const float* xbase = x + b * CHW + hw0;

        // esum partial (blocks 0-15 cover ecs[0..4095])
        int gn = blk * 256 + t;
        if (gn < NUM_K) {
            float v = ecs[gn];
#pragma unroll
            for (int m = 1; m < 64; m <<= 1) v += __shfl_xor(v, m, 64);
            if ((t & 63) == 0) atomicAdd(esum, v);
        }

#pragma unroll
        for (int j = 0; j < 16; ++j) {
            int c = wv + j * 4;
            xs[lane][c] = xbase[c * HWDIM + lane];
        }

        // inline combine (verbatim slice-merge + near-tie flag)
        if (t < 64) {
            int n = n0 + t;
            u64 ka = keys[n], kb = keys[NVEC + n];
            u64 km = ka < kb ? ka : kb;        // equal score -> lower code
            int idx = (int)(km & 0xFFFFFFFFu);
            sidx[t] = idx;
            out[O_IDX + n] = (float)idx;
            float* cr = (blk & 1) ? counts1 : counts0;
            atomicAdd(&cr[idx], 1.0f);
            float a1 = __uint_as_float((unsigned)(ka >> 32));  // biased > 0
            float c1 = __uint_as_float((unsigned)(kb >> 32));
            float lo = fminf(a1, c1), hi = fmaxf(a1, c1);
            float m2 = fminf(fminf(b2s[n], b2s[NVEC + n]), hi);
            if (m2 - lo < TAUH) { int p = atomicAdd(rcnt, 1); rlist[p] = n; }
        }
        __syncthreads();

        float* dwr = (blk & 1) ? dw1 : dw0;
        float lsum = 0.f;
#pragma unroll
        for (int j = 0; j < 16; ++j) {
            int c = wv + j * 4;
            float xvv = xs[lane][c];
            float qv = w[sidx[lane] * CDIM + c];
            float d = qv - xvv;
            out[O_Q + b * CHW + c * HWDIM + hw0 + lane] = xvv + d;
            lsum = fmaf(d, d, lsum);
        }
        red[t] = lsum;
        __syncthreads();
        for (int s = 128; s > 0; s >>= 1) {
            if (t < s) red[t] += red[t + s];
            __syncthreads();
        }
        if (t == 0) atomicAdd(loss_acc, red[0]);

        for (int i = 0; i < 16; ++i) {
            int nl = wv * 16 + i;
            atomicAdd(&dwr[sidx[nl] * CDIM + lane], xs[nl][lane]);
        }
    }

    grid_barrier(&bars[0]);

    // ================= phase 2: rescue patch (r11-verified) =================
    {
        int cnt = *rcnt;
        for (int i = blk; i < cnt; i += gridDim.x) {
            int n = rlist[i];
            int b = n >> 12, hw = n & (HWDIM - 1);
            if (t < CDIM) xv[t] = x[b * CHW + t * HWDIM + hw];
            __syncthreads();
            u64 local = ~0ull;
            for (int k = t; k < NUM_K; k += 256) {
                const float* wr = w + k * CDIM;
                float d0 = 0.f, d1 = 0.f, d2 = 0.f, d3 = 0.f;
#pragma unroll
                for (int c = 0; c < CDIM; c += 4) {
                    d0 = fmaf(xv[c + 0], wr[c + 0], d0);
                    d1 = fmaf(xv[c + 1], wr[c + 1], d1);
                    d2 = fmaf(xv[c + 2], wr[c + 2], d2);
                    d3 = fmaf(xv[c + 3], wr[c + 3], d3);
                }
                // biased s/2 scale (wsqh includes SBIAS): ordering identical
                float s = wsqh[k] - ((d0 + d1) + (d2 + d3));
                u64 key = ((u64)f2ord(s) << 32) | (unsigned)k;  // lower k wins
                local = local < key ? local : key;
            }
            rk[t] = local;
            __syncthreads();
            for (int s = 128; s > 0; s >>= 1) {
                if (t < s) rk[t] = rk[t] < rk[t + s] ? rk[t] : rk[t + s];
                __syncthreads();
            }
            int knew = (int)(rk[0] & 0xFFFFFFFFu);
            int kold = (int)out[O_IDX + n];
            if (knew != kold) {
                if (t == 0) {
                    out[O_IDX + n] = (float)knew;
                    atomicAdd(&counts0[kold], -1.0f);
                    atomicAdd(&counts0[knew],  1.0f);
                }
                if (t < CDIM) {
                    int c = t;
                    float xvv = xv[c];
                    float dn = w[knew * CDIM + c] - xvv;
                    float dold = w[kold * CDIM + c] - xvv;
                    out[O_Q + b * CHW + c * HWDIM + hw] = xvv + dn;
                    atomicAdd(&dw0[kold * CDIM + c], -xvv);
                    atomicAdd(&dw0[knew * CDIM + c],  xvv);
                    float dl = dn * dn - dold * dold;
#pragma unroll
                    for (int m = 1; m < 64; m <<= 1) dl += __shfl_xor(dl, m, 64);
                    if (c == 0) atomicAdd(loss_acc, dl);
                }
            }
            __syncthreads();
        }
    }

    grid_barrier(&bars[1]);

    // ================= phase 3: finalize (r11-verified) =====================
    {
        int e = blk * 256 + t;                 // 0..262143 == CHW exactly
        int k = e >> 6;                        // wave-uniform
        float cntk = counts0[k] + counts1[k];
        float ncs = 0.99f * ecs[k] + 0.01f * cntk;
        if ((e & 63) == 0) out[O_CS + k] = ncs;
        if (e == 0) out[O_LOSS] = 0.25f * loss_acc[0] / 4194304.0f;
        float n = 0.99f * esum[0] + 0.01f * 65536.0f;
        float cs = (ncs + 1e-5f) / (n + NUM_K * 1e-5f) * n;
        float ew = 0.99f * ema_w[e] + 0.01f * (dw0[e] + dw1[e]);
        out[O_EW + e] = ew;
        out[O_W + e] = ew / cs;
    }
}

extern "C" void kernel_launch(void* const* d_in, const int* in_sizes, int n_in,
                              void* d_out, int out_size, void* d_ws, size_t ws_size,
                              hipStream_t stream) {
    const float* x     = (const float*)d_in[0];
    const float* w     = (const float*)d_in[1];
    const float* ecs   = (const float*)d_in[2];
    const float* ema_w = (const float*)d_in[3];
    float* out = (float*)d_out;
    float* ws  = (float*)d_ws;

    float* wsqh    = ws + W_WSQ;
    float* counts0 = ws + W_CNT0;
    float* counts1 = ws + W_CNT1;
    float* loss_a  = ws + W_LOSS;
    float* esum    = ws + W_ESUM;
    int*   rcnt    = (int*)(ws + W_RCNT);
    int*   bars    = (int*)(ws + W_BAR0);      // bars[0], bars[1]
    int*   rlist   = (int*)(ws + W_RLIST);
    float* dw0     = ws + W_DW0;
    float* dw1     = ws + W_DW1;

    // scratch overlays in out (r8/r11-proven placement, see layout comment):
    __bf16* wh  = (__bf16*)out;                // [0, 262144) floats
    __bf16* wl  = wh + NUM_K * CDIM;
    u64*   keys = (u64*)(out + 4259842);       // out-tail, 8B-aligned
    float* b2s  = out + 4521986;

    prep_kernel<<<NUM_K / 4, 256, 0, stream>>>(w, wsqh, wh, wl, counts0, dw0, dw1);
    argmin_mfma<<<dim3(NVEC / 128, 2), 128, 32768, stream>>>(x, wh, wl, wsqh, keys, b2s);
    tail_fused<<<NVEC / 64, 256, 0, stream>>>(x, w, keys, b2s, wsqh, ecs, ema_w,
                                              esum, out, counts0, counts1,
                                              dw0, dw1, rcnt, rlist, loss_a, bars);
}

// Round 15
// 244.658 us; speedup vs baseline: 2.0850x; 2.0850x over previous
//
#include <hip/hip_runtime.h>

#define NUM_K   4096
#define CDIM    64
#define HWDIM   4096            // 64*64
#define NVEC    65536           // 16 * 64 * 64
#define CHW     (CDIM * HWDIM)  // 262144
#define KT      32              // codes per k-tile
#define NKT_SL  64              // k-tiles per slice (2048 codes)
// rescue margin on biased s/2 scale: bf16-split budget 2e-3 (validated r4-r6)
// + 7-bit mask granularity q<=3.9e-3 (scores < 512) + slack
#define TAUH    6e-3f
#define SBIAS   128.0f          // score bias: s' = 128 + (wsq - 2 x.w)/2 > 0 always
#define RLMAX   16384           // rlist capacity (measured rcnt ~250; 64x margin)

// ---- output layout (floats, concatenated in reference return order) ----
#define O_Q     0               // quantized_ste  [16,64,64,64] = 4194304
#define O_LOSS  4194304         // scalar
#define O_IDX   4194305         // encoding_indices [16,64,64] = 65536 (as float)
#define O_W     4259841         // new_weight   [4096,64] = 262144
#define O_CS    4521985         // new_cluster_size [4096]
#define O_EW    4526081         // new_ema_w    [4096,64] = 262144
// Scratch overlays in out (strictly ordered):
//  - wh/wl bf16 codebook: out floats [0, 262144)  (prep W -> argmin R ->
//    overwritten by assign's O_Q writes)
//  - keys[2][NVEC] u64: out floats [4259842, 4521986)  (argmin W -> assign R
//    -> finalize overwrites O_W; assign writes only O_Q/O_IDX, disjoint)
//  - dw replica 2: out[O_EW..O_EW+CHW)  (prep zeroes -> assign atomics ->
//    finalize reads each element then overwrites it; same-thread RAW, r9-proven)

// ---- workspace layout (floats) ----
#define W_WSQ    0               // wsq/2 + SBIAS [4096]
#define W_CNT0   4096            // counts replicas 0..3 [4][4096]
#define W_CNT1   8192
#define W_CNT2   12288
#define W_CNT3   16384
#define W_LOSS   20480           // loss, esum, rcnt, pad
#define W_ESUM   20481
#define W_RCNT   20482
#define W_RLIST  20484           // flagged-vector list int[RLMAX]
#define W_DW0    36868           // dw replica 0 [262144]
#define W_DW1    299012          // dw replica 1 [262144]
#define W_B2     561156          // b2s [2][65536] (moved out of the out-tail)
// high-water: 692228 floats = 2.77 MB (under proven 2.92 MB)

typedef unsigned long long u64;
typedef __bf16 bf16x8 __attribute__((ext_vector_type(8)));
typedef float  f32x4  __attribute__((ext_vector_type(4)));

__device__ __forceinline__ unsigned f2ord(float f) {
    unsigned u = __float_as_uint(f);
    return (u & 0x80000000u) ? ~u : (u | 0x80000000u);
}
__device__ __forceinline__ unsigned umn(unsigned a, unsigned b) { return a < b ? a : b; }
__device__ __forceinline__ unsigned umx(unsigned a, unsigned b) { return a > b ? a : b; }

// Per codebook row: biased wsq/2 + SBIAS (fp32) + bf16 hi/lo split copies.
// Zeroes counts replicas + scalars + all three dw replicas (grid = CHW thr;
// dw2 overlays out[O_EW], zeroed here per the r9-proven pattern).
__global__ void __launch_bounds__(256)
prep_kernel(const float* __restrict__ w, float* __restrict__ wsqh,
            __bf16* __restrict__ wh, __bf16* __restrict__ wl,
            float* __restrict__ zero_area,
            float* __restrict__ dw0, float* __restrict__ dw1,
            float* __restrict__ dw2) {
    int gid = blockIdx.x * 256 + threadIdx.x;
    dw0[gid] = 0.f;                            // gid in [0, CHW)
    dw1[gid] = 0.f;
    dw2[gid] = 0.f;                            // out[O_EW + gid]
    if (gid < 16388) zero_area[gid] = 0.f;     // counts0..3 + loss/esum/rcnt/pad
    int wv = threadIdx.x >> 6, lane = threadIdx.x & 63;
    int row = blockIdx.x * 4 + wv;
    float v = w[row * CDIM + lane];
    __bf16 h = (__bf16)v;
    __bf16 l = (__bf16)(v - (float)h);         // v - hi exact in fp32
    wh[row * CDIM + lane] = h;
    wl[row * CDIM + lane] = l;
    float sq = v * v;
#pragma unroll
    for (int m = 1; m < 64; m <<= 1) sq += __shfl_xor(sq, m, 64);
    if (lane == 0) wsqh[row] = 0.5f * sq + SBIAS;
}

// One k-tile body: 48 MFMA (4 m-slots x 2 code-halves x bf16x3-split K=64)
// + packed-u32 top-2 update. Identical numerics to the verified kernel.
__device__ __forceinline__ void kt_body(const bf16x8 (&B)[8],
                                        const bf16x8 (&ah)[4][2],
                                        const bf16x8 (&al)[4][2],
                                        unsigned (&b1k)[16], unsigned (&b2k)[16],
                                        float wA, float wB, int kt) {
    unsigned tA = (unsigned)(kt * 2), tB = tA + 1;
#pragma unroll
    for (int m = 0; m < 4; ++m) {
        f32x4 accA = {wA, wA, wA, wA};     // acc = SBIAS + wsq/2 - dot  (> 0)
        f32x4 accB = {wB, wB, wB, wB};
        accA = __builtin_amdgcn_mfma_f32_16x16x32_bf16(ah[m][0], B[0], accA, 0, 0, 0);
        accA = __builtin_amdgcn_mfma_f32_16x16x32_bf16(ah[m][1], B[1], accA, 0, 0, 0);
        accA = __builtin_amdgcn_mfma_f32_16x16x32_bf16(al[m][0], B[0], accA, 0, 0, 0);
        accA = __builtin_amdgcn_mfma_f32_16x16x32_bf16(al[m][1], B[1], accA, 0, 0, 0);
        accA = __builtin_amdgcn_mfma_f32_16x16x32_bf16(ah[m][0], B[4], accA, 0, 0, 0);
        accA = __builtin_amdgcn_mfma_f32_16x16x32_bf16(ah[m][1], B[5], accA, 0, 0, 0);
        accB = __builtin_amdgcn_mfma_f32_16x16x32_bf16(ah[m][0], B[2], accB, 0, 0, 0);
        accB = __builtin_amdgcn_mfma_f32_16x16x32_bf16(ah[m][1], B[3], accB, 0, 0, 0);
        accB = __builtin_amdgcn_mfma_f32_16x16x32_bf16(al[m][0], B[2], accB, 0, 0, 0);
        accB = __builtin_amdgcn_mfma_f32_16x16x32_bf16(al[m][1], B[3], accB, 0, 0, 0);
        accB = __builtin_amdgcn_mfma_f32_16x16x32_bf16(ah[m][0], B[6], accB, 0, 0, 0);
        accB = __builtin_amdgcn_mfma_f32_16x16x32_bf16(ah[m][1], B[7], accB, 0, 0, 0);
#pragma unroll
        for (int r = 0; r < 4; ++r) {
            unsigned ka = (__float_as_uint(accA[r]) & 0xFFFFFF80u) | tA;  // v_and_or_b32
            unsigned kb = (__float_as_uint(accB[r]) & 0xFFFFFF80u) | tB;
            unsigned lo = umn(ka, kb), hi = umx(ka, kb);
            int s8 = m * 4 + r;
            b2k[s8] = umn(umn(b2k[s8], umx(b1k[s8], lo)), hi);  // min3 fuse
            b1k[s8] = umn(b1k[s8], lo);
        }
    }
}

// Fused bf16x3-split MFMA GEMM + argmin, K-split into 2 slices (grid.y).
// FROZEN at the round-2 verified structure (113.5us best): 128 thr / 2 waves,
// 64 rows per wave (4 m-slots), reg-staged B ping-pong with per-kt barrier,
// unpadded xs with XOR swizzle (bank-conflict-free, 32 KB LDS).
__global__ void __launch_bounds__(128, 3)
argmin_mfma(const float* __restrict__ x,
            const __bf16* __restrict__ wh_g, const __bf16* __restrict__ wl_g,
            const float* __restrict__ wsqh_g,
            u64* __restrict__ keys, float* __restrict__ b2s) {
    extern __shared__ __bf16 smem[];           // 32768 B
    char* xs_h = (char*)smem;                  // [128 rows][128 B] swizzled
    char* xs_l = xs_h + 16384;
    __bf16* bs = smem;                         // overlay: [2][4096] after xs dead

    int t = threadIdx.x, wv = t >> 6, lane = t & 63;
    int n0 = blockIdx.x * 128;
    int b = n0 >> 12, hw0 = n0 & (HWDIM - 1);
    int kbase = blockIdx.y * (NUM_K / 2);
    int slice = blockIdx.y;

    // 1) stage -x hi/lo; row = t, 8 col-groups of 8 ch; b128 swizzled writes.
    {
        const float* xb = x + b * CHW + hw0 + t;
#pragma unroll
        for (int j = 0; j < 8; ++j) {
            bf16x8 hi, lo;
#pragma unroll
            for (int cc = 0; cc < 8; ++cc) {
                float v = -xb[(j * 8 + cc) * HWDIM];
                __bf16 h = (__bf16)v;
                hi[cc] = h;
                lo[cc] = (__bf16)(v - (float)h);   // exact in fp32
            }
            int bo = (t * 128 + j * 16) ^ ((t & 7) << 4);
            *(bf16x8*)(xs_h + bo) = hi;
            *(bf16x8*)(xs_l + bo) = lo;
        }
    }
    __syncthreads();

    int nn = lane & 15, q4 = lane >> 4;
    // 2) A-frags -> registers (64 rows per wave, 4 m-slots; swizzled b128 reads)
    bf16x8 ah[4][2], al[4][2];
#pragma unroll
    for (int m = 0; m < 4; ++m) {
        int id = wv * 64 + m * 16 + nn;
#pragma unroll
        for (int ch = 0; ch < 2; ++ch) {
            int bo = (id * 128 + (q4 + ch * 4) * 16) ^ ((id & 7) << 4);
            ah[m][ch] = *(const bf16x8*)(xs_h + bo);
            al[m][ch] = *(const bf16x8*)(xs_l + bo);
        }
    }
    __syncthreads();   // all waves done reading xs -> LDS reusable for B tiles

    // B staging map (128 thr, 4 chunks each): LDS layout per tile:
    // hiA [0,1024) hiB [1024,2048) loA [2048,3072) loB [3072,4096) elems;
    // writes at t*16 B consecutive (conflict-free); reads 16B/lane chunks.
    int sr = t & 15, sj = (t >> 4) & 7;
    long goff0 = (long)sr * 64 + sj * 8;        // codes 0-15 half
    long goff1 = (long)(16 + sr) * 64 + sj * 8; // codes 16-31 half
    {
        long g = (long)kbase * 64;
        *(bf16x8*)(bs + t * 8)        = *(const bf16x8*)(wh_g + g + goff0);
        *(bf16x8*)(bs + 1024 + t * 8) = *(const bf16x8*)(wh_g + g + goff1);
        *(bf16x8*)(bs + 2048 + t * 8) = *(const bf16x8*)(wl_g + g + goff0);
        *(bf16x8*)(bs + 3072 + t * 8) = *(const bf16x8*)(wl_g + g + goff1);
    }
    __syncthreads();

    unsigned b1k[16], b2k[16];
#pragma unroll
    for (int s = 0; s < 16; ++s) { b1k[s] = 0xFFFFFFFFu; b2k[s] = 0xFFFFFFFFu; }

    for (int kt = 0; kt < NKT_SL; ++kt) {
        __bf16* base = bs + (kt & 1) * 4096;
        bf16x8 st0h, st1h, st0l, st1l;
        bool pre = (kt + 1 < NKT_SL);
        if (pre) {   // issue next-tile global loads early; latency spans MFMA
            long g = (long)(kbase + (kt + 1) * KT) * 64;
            st0h = *(const bf16x8*)(wh_g + g + goff0);
            st1h = *(const bf16x8*)(wh_g + g + goff1);
            st0l = *(const bf16x8*)(wl_g + g + goff0);
            st1l = *(const bf16x8*)(wl_g + g + goff1);
        }

        int k0 = kbase + kt * KT;
        float wA = wsqh_g[k0 + nn];            // biased table, L1-hot
        float wB = wsqh_g[k0 + 16 + nn];

        int o1 = (q4 * 16 + nn) * 8, o2 = ((q4 + 4) * 16 + nn) * 8;
        bf16x8 B[8];
        B[0] = *(const bf16x8*)(base + o1);            // bh0A
        B[1] = *(const bf16x8*)(base + o2);            // bh1A
        B[2] = *(const bf16x8*)(base + 1024 + o1);     // bh0B
        B[3] = *(const bf16x8*)(base + 1024 + o2);     // bh1B
        B[4] = *(const bf16x8*)(base + 2048 + o1);     // bl0A
        B[5] = *(const bf16x8*)(base + 2048 + o2);     // bl1A
        B[6] = *(const bf16x8*)(base + 3072 + o1);     // bl0B
        B[7] = *(const bf16x8*)(base + 3072 + o2);     // bl1B

        kt_body(B, ah, al, b1k, b2k, wA, wB, kt);

        if (pre) {
            __bf16* nb = bs + ((kt + 1) & 1) * 4096;
            *(bf16x8*)(nb + t * 8)        = st0h;
            *(bf16x8*)(nb + 1024 + t * 8) = st1h;
            *(bf16x8*)(nb + 2048 + t * 8) = st0l;
            *(bf16x8*)(nb + 3072 + t * 8) = st1l;
        }
        __syncthreads();
    }

    // unpack: tag*16 == kt*32 + half*16, so code = (kbase+nn) + tag*16
    float s1[16], sb2[16]; int code[16];
#pragma unroll
    for (int s = 0; s < 16; ++s) {
        s1[s]  = __uint_as_float(b1k[s] & 0xFFFFFF80u);
        sb2[s] = __uint_as_float(b2k[s] & 0xFFFFFF80u);
        code[s] = (kbase + nn) + (int)(b1k[s] & 0x7Fu) * 16;
    }
    // cross-lane merge over the 16 code-classes (lanes sharing q4)
#pragma unroll
    for (int msk = 1; msk < 16; msk <<= 1) {
#pragma unroll
        for (int s = 0; s < 16; ++s) {
            float os1 = __shfl_xor(s1[s], msk, 64);
            float ob2 = __shfl_xor(sb2[s], msk, 64);
            int   oc  = __shfl_xor(code[s], msk, 64);
            sb2[s] = fminf(fminf(sb2[s], ob2), fmaxf(s1[s], os1));
            if (os1 < s1[s]) code[s] = oc;   // exact ties -> margin 0 -> rescued
            s1[s] = fminf(s1[s], os1);
        }
    }
    if (nn == 0) {
#pragma unroll
        for (int s = 0; s < 16; ++s) {
            int m = s >> 2, r = s & 3;
            int v = n0 + wv * 64 + m * 16 + q4 * 4 + r;
            keys[slice * NVEC + v] = ((u64)__float_as_uint(s1[s]) << 32) | (unsigned)code[s];
            b2s[slice * NVEC + v]  = sb2[s];
        }
    }
}

// FUSED combine + assign (r11-verified body). THIS ROUND: dw atomics fan
// over 3 replicas (blockIdx%3; replica 2 overlays out[O_EW]) and counts
// over 4 replicas (blockIdx&3) -- same float-add multiset, less same-
// address RMW contention at the coherent point.
__global__ void __launch_bounds__(256)
assign_fused(const float* __restrict__ x, const float* __restrict__ w,
             const u64* __restrict__ keys, const float* __restrict__ b2s,
             const float* __restrict__ ecs, float* __restrict__ esum,
             float* __restrict__ out, float* __restrict__ counts,
             float* __restrict__ dw0, float* __restrict__ dw1,
             int* __restrict__ rcnt, int* __restrict__ rlist,
             float* __restrict__ loss_acc) {
    __shared__ float xs[64][CDIM + 1];
    __shared__ int   sidx[64];
    __shared__ float red[256];

    int t  = threadIdx.x;
    int n0 = blockIdx.x * 64;
    int b  = n0 >> 12;
    int hw0 = n0 & (HWDIM - 1);
    const float* xbase = x + b * CHW + hw0;

    // esum partial (blocks 0-15 cover ecs[0..4095])
    int gn = blockIdx.x * 256 + t;
    if (gn < NUM_K) {
        float v = ecs[gn];
#pragma unroll
        for (int m = 1; m < 64; m <<= 1) v += __shfl_xor(v, m, 64);
        if ((t & 63) == 0) atomicAdd(esum, v);
    }

    int lane = t & 63, wv = t >> 6;
#pragma unroll
    for (int j = 0; j < 16; ++j) {
        int c = wv + j * 4;
        xs[lane][c] = xbase[c * HWDIM + lane];
    }

    // inline combine (verbatim slice-merge + near-tie flag)
    if (t < 64) {
        int n = n0 + t;
        u64 ka = keys[n], kb = keys[NVEC + n];
        u64 km = ka < kb ? ka : kb;        // equal score -> lower code (slice 0)
        int idx = (int)(km & 0xFFFFFFFFu);
        sidx[t] = idx;
        out[O_IDX + n] = (float)idx;
        atomicAdd(&counts[(blockIdx.x & 3) * NUM_K + idx], 1.0f);
        float a1 = __uint_as_float((unsigned)(ka >> 32));  // biased > 0: monotone
        float c1 = __uint_as_float((unsigned)(kb >> 32));
        float lo = fminf(a1, c1), hi = fmaxf(a1, c1);
        float m2 = fminf(fminf(b2s[n], b2s[NVEC + n]), hi);
        if (m2 - lo < TAUH) {
            int p = atomicAdd(rcnt, 1);
            if (p < RLMAX) rlist[p] = n;
        }
    }
    __syncthreads();

    int r3 = blockIdx.x % 3;
    float* dwr = (r3 == 0) ? dw0 : (r3 == 1 ? dw1 : (out + O_EW));
    float lsum = 0.f;
#pragma unroll
    for (int j = 0; j < 16; ++j) {
        int c = wv + j * 4;
        float xv = xs[lane][c];
        float qv = w[sidx[lane] * CDIM + c];
        float d = qv - xv;
        out[O_Q + b * CHW + c * HWDIM + hw0 + lane] = xv + d;
        lsum = fmaf(d, d, lsum);
    }
    red[t] = lsum;
    __syncthreads();
    for (int s = 128; s > 0; s >>= 1) {
        if (t < s) red[t] += red[t + s];
        __syncthreads();
    }
    if (t == 0) atomicAdd(loss_acc, red[0]);

    for (int i = 0; i < 16; ++i) {
        int nl = wv * 16 + i;
        atomicAdd(&dwr[sidx[nl] * CDIM + lane], xs[nl][lane]);  // wave-coalesced row
    }
}

// Exact fp32 re-argmin for flagged vectors, run AFTER assign as a PATCH
// (r11-verified): only when the exact index differs, fix O_IDX, the O_Q
// row, counts (+/-1 on replica 0), dw (+/-x on replica 0), loss (delta).
__global__ void __launch_bounds__(256)
rescue_patch(const float* __restrict__ x, const float* __restrict__ w,
             const float* __restrict__ wsqh,
             const int* __restrict__ rcnt, const int* __restrict__ rlist,
             float* __restrict__ out, float* __restrict__ counts0,
             float* __restrict__ dw0, float* __restrict__ loss_acc) {
    __shared__ float xv[CDIM];
    __shared__ u64 rk[256];
    int t = threadIdx.x;
    int cnt = *rcnt;
    if (cnt > RLMAX) cnt = RLMAX;
    for (int i = blockIdx.x; i < cnt; i += gridDim.x) {
        int n = rlist[i];
        int b = n >> 12, hw = n & (HWDIM - 1);
        if (t < CDIM) xv[t] = x[b * CHW + t * HWDIM + hw];
        __syncthreads();
        u64 local = ~0ull;
        for (int k = t; k < NUM_K; k += 256) {
            const float* wr = w + k * CDIM;
            float d0 = 0.f, d1 = 0.f, d2 = 0.f, d3 = 0.f;
#pragma unroll
            for (int c = 0; c < CDIM; c += 4) {
                d0 = fmaf(xv[c + 0], wr[c + 0], d0);
                d1 = fmaf(xv[c + 1], wr[c + 1], d1);
                d2 = fmaf(xv[c + 2], wr[c + 2], d2);
                d3 = fmaf(xv[c + 3], wr[c + 3], d3);
            }
            // biased s/2 scale (wsqh includes SBIAS): ordering identical
            float s = wsqh[k] - ((d0 + d1) + (d2 + d3));
            u64 key = ((u64)f2ord(s) << 32) | (unsigned)k; // lower k wins ties
            local = local < key ? local : key;
        }
        rk[t] = local;
        __syncthreads();
        for (int s = 128; s > 0; s >>= 1) {
            if (t < s) rk[t] = rk[t] < rk[t + s] ? rk[t] : rk[t + s];
            __syncthreads();
        }
        int knew = (int)(rk[0] & 0xFFFFFFFFu);
        int kold = (int)out[O_IDX + n];
        if (knew != kold) {
            if (t == 0) {
                out[O_IDX + n] = (float)knew;
                atomicAdd(&counts0[kold], -1.0f);
                atomicAdd(&counts0[knew],  1.0f);
            }
            if (t < CDIM) {
                int c = t;
                float xvv = xv[c];
                float dn = w[knew * CDIM + c] - xvv;
                float dold = w[kold * CDIM + c] - xvv;
                out[O_Q + b * CHW + c * HWDIM + hw] = xvv + dn;
                atomicAdd(&dw0[kold * CDIM + c], -xvv);
                atomicAdd(&dw0[knew * CDIM + c],  xvv);
                float dl = dn * dn - dold * dold;
#pragma unroll
                for (int m = 1; m < 64; m <<= 1) dl += __shfl_xor(dl, m, 64);
                if (c == 0) atomicAdd(loss_acc, dl);
            }
        }
        __syncthreads();
    }
}

// One fused elementwise pass over [4096,64]: new_cluster_size, new_ema_w,
// new_weight, loss. counts = sum of 4 replicas; dw = dw0 + dw1 + out[O_EW+e]
// (replica 2 read BEFORE the same thread overwrites that slot -- r9-proven).
__global__ void __launch_bounds__(256)
finalize_all(const float* __restrict__ ecs, const float* __restrict__ counts,
             const float* __restrict__ ema_w,
             const float* __restrict__ dw0, const float* __restrict__ dw1,
             const float* __restrict__ loss_acc, const float* __restrict__ esum,
             float* out) {
    int e = blockIdx.x * 256 + threadIdx.x;   // 0..262143
    int k = e >> 6;                            // wave-uniform
    float dwv = (dw0[e] + dw1[e]) + out[O_EW + e];
    float cntk = (counts[k] + counts[NUM_K + k])
               + (counts[2 * NUM_K + k] + counts[3 * NUM_K + k]);
    float ncs = 0.99f * ecs[k] + 0.01f * cntk;
    if ((e & 63) == 0) out[O_CS + k] = ncs;
    if (e == 0) out[O_LOSS] = 0.25f * loss_acc[0] / 4194304.0f;
    float n = 0.99f * esum[0] + 0.01f * 65536.0f;
    float cs = (ncs + 1e-5f) / (n + NUM_K * 1e-5f) * n;
    float ew = 0.99f * ema_w[e] + 0.01f * dwv;
    out[O_EW + e] = ew;
    out[O_W + e] = ew / cs;
}

extern "C" void kernel_launch(void* const* d_in, const int* in_sizes, int n_in,
                              void* d_out, int out_size, void* d_ws, size_t ws_size,
                              hipStream_t stream) {
    const float* x     = (const float*)d_in[0];
    const float* w     = (const float*)d_in[1];
    const float* ecs   = (const float*)d_in[2];
    const float* ema_w = (const float*)d_in[3];
    float* out = (float*)d_out;
    float* ws  = (float*)d_ws;

    float* wsqh   = ws + W_WSQ;
    float* counts = ws + W_CNT0;               // 4 replicas, contiguous
    float* loss_a = ws + W_LOSS;
    float* esum   = ws + W_ESUM;
    int*   rcnt   = (int*)(ws + W_RCNT);
    int*   rlist  = (int*)(ws + W_RLIST);
    float* dw0    = ws + W_DW0;
    float* dw1    = ws + W_DW1;
    float* b2s    = ws + W_B2;

    // scratch overlays in out (see layout comment):
    __bf16* wh  = (__bf16*)out;                // [0, 262144) floats
    __bf16* wl  = wh + NUM_K * CDIM;
    u64*   keys = (u64*)(out + 4259842);       // out-tail, 8B-aligned
    float* dw2  = out + O_EW;                  // dw replica 2

    prep_kernel<<<NUM_K / 4, 256, 0, stream>>>(w, wsqh, wh, wl, counts,
                                               dw0, dw1, dw2);
    argmin_mfma<<<dim3(NVEC / 128, 2), 128, 32768, stream>>>(x, wh, wl, wsqh, keys, b2s);
    assign_fused<<<NVEC / 64, 256, 0, stream>>>(x, w, keys, b2s, ecs, esum, out,
                                                counts, dw0, dw1,
                                                rcnt, rlist, loss_a);
    rescue_patch<<<256, 256, 0, stream>>>(x, w, wsqh, rcnt, rlist, out,
                                          counts, dw0, loss_a);
    finalize_all<<<CHW / 256, 256, 0, stream>>>(ecs, counts, ema_w,
                                                dw0, dw1, loss_a, esum, out);
}